// Round 13
// baseline (1103.736 us; speedup 1.0000x reference)
//
#include <hip/hip_runtime.h>
#include <hip/hip_bf16.h>

#define NN 100000
#define NE 3200000
#define ET (NE + NN)
#define NG 64
#define BINBITS 10
#define NBINS 98   // ceil(100000/1024)
#define EPB 16
#define LOG2E 1.44269504088896f

__device__ __forceinline__ unsigned bfr(float x) {  // fp32 -> bf16 bits, RNE
  unsigned u = __float_as_uint(x);
  return (u + 0x7FFFu + ((u >> 16) & 1u)) >> 16;
}

__device__ __forceinline__ unsigned fkey(float x) {  // orderable-uint encode
  unsigned b = __float_as_uint(x);
  return (b & 0x80000000u) ? ~b : (b | 0x80000000u);
}

__device__ __forceinline__ float gmax_decode(unsigned k) {
  return __uint_as_float((k & 0x80000000u) ? (k & 0x7FFFFFFFu) : ~k);
}

// ---------------- CSR build ----------------
__global__ void init_counts_k(int* counts) {
  int i = blockIdx.x * 256 + threadIdx.x;
  if (i < NN) counts[i] = 1;  // self loop
}

__global__ void count_k(const int* __restrict__ dst, int* __restrict__ counts) {
  int i = blockIdx.x * 256 + threadIdx.x;
  if (i < NE) atomicAdd(&counts[dst[i]], 1);
}

__global__ __launch_bounds__(1024) void scan1_k(const int* __restrict__ cnt, int* __restrict__ csum) {
  __shared__ int lds[1024];
  int i = blockIdx.x * 1024 + threadIdx.x;
  lds[threadIdx.x] = (i < NN) ? cnt[i] : 0;
  __syncthreads();
  for (int off = 512; off > 0; off >>= 1) {
    if (threadIdx.x < off) lds[threadIdx.x] += lds[threadIdx.x + off];
    __syncthreads();
  }
  if (threadIdx.x == 0) csum[blockIdx.x] = lds[0];
}

__global__ __launch_bounds__(128) void scan2_k(int* csum, int nch) {
  __shared__ int lds[128];
  int v = (threadIdx.x < nch) ? csum[threadIdx.x] : 0;
  lds[threadIdx.x] = v;
  __syncthreads();
  for (int off = 1; off < 128; off <<= 1) {
    int t = (threadIdx.x >= off) ? lds[threadIdx.x - off] : 0;
    __syncthreads();
    lds[threadIdx.x] += t;
    __syncthreads();
  }
  if (threadIdx.x < nch) csum[threadIdx.x] = lds[threadIdx.x] - v;  // exclusive
}

__global__ __launch_bounds__(1024) void scan3_k(const int* __restrict__ cnt, const int* __restrict__ csum,
                                                int* __restrict__ indptr, int* __restrict__ cursor) {
  __shared__ int lds[1024];
  int i = blockIdx.x * 1024 + threadIdx.x;
  int v = (i < NN) ? cnt[i] : 0;
  lds[threadIdx.x] = v;
  __syncthreads();
  for (int off = 1; off < 1024; off <<= 1) {
    int t = (threadIdx.x >= off) ? lds[threadIdx.x - off] : 0;
    __syncthreads();
    lds[threadIdx.x] += t;
    __syncthreads();
  }
  int excl = csum[blockIdx.x] + lds[threadIdx.x] - v;
  if (i < NN) { indptr[i] = excl; cursor[i] = excl; }
  else if (i == NN) indptr[NN] = ET;
}

__global__ void bininit_k(const int* __restrict__ indptr, int* __restrict__ binbase, int* __restrict__ bincur) {
  int b = threadIdx.x;
  if (b <= NBINS) {
    int node = b << BINBITS; if (node > NN) node = NN;
    int v = indptr[node];
    binbase[b] = v;
    if (b < NBINS) bincur[b] = v;
  }
}

// Pass A: bin edges by dst-range into staging buffer (packed (s<<10)|(d&1023))
__global__ __launch_bounds__(256) void binA_k(const int* __restrict__ ei, int* __restrict__ bincur,
                                              unsigned* __restrict__ binbuf) {
  __shared__ int lhist[NBINS], lbase[NBINS];
  int t = threadIdx.x;
  for (int i = t; i < NBINS; i += 256) lhist[i] = 0;
  __syncthreads();
  long base = (long)blockIdx.x * (256 * EPB);
  unsigned pk[EPB]; int bn[EPB];
  #pragma unroll
  for (int j = 0; j < EPB; j++) {
    long i = base + j * 256 + t;
    if (i < ET) {
      int s, d;
      if (i < NE) { s = ei[i]; d = ei[NE + i]; }
      else { s = (int)(i - NE); d = s; }
      int b = d >> BINBITS;
      bn[j] = b;
      pk[j] = ((unsigned)s << BINBITS) | (unsigned)(d & 1023);
      atomicAdd(&lhist[b], 1);
    } else bn[j] = -1;
  }
  __syncthreads();
  for (int i = t; i < NBINS; i += 256) {
    int c = lhist[i];
    lbase[i] = c ? atomicAdd(&bincur[i], c) : 0;
    lhist[i] = 0;
  }
  __syncthreads();
  #pragma unroll
  for (int j = 0; j < EPB; j++) {
    if (bn[j] >= 0) {
      int off = atomicAdd(&lhist[bn[j]], 1);
      binbuf[lbase[bn[j]] + off] = pk[j];
    }
  }
}

// Pass B: per-bin localized scatter to final CSR slots (L2-resident region per bin)
#define SEGS 8
__global__ __launch_bounds__(256) void binB_k(const unsigned* __restrict__ binbuf, const int* __restrict__ binbase,
                                              int* __restrict__ cursor, int* __restrict__ srcs) {
  int r = blockIdx.x & 7;
  int m = blockIdx.x >> 3;
  int q = m / SEGS, seg = m % SEGS;
  int bin = q * 8 + r;
  if (bin >= NBINS) return;
  int b0 = binbase[bin], b1 = binbase[bin + 1];
  int n = b1 - b0;
  int per = (n + SEGS - 1) / SEGS;
  int e0 = b0 + seg * per;
  int e1 = min(e0 + per, b1);
  int dbase = bin << BINBITS;
  for (int i = e0 + threadIdx.x; i < e1; i += 256) {
    unsigned p = binbuf[i];
    int d = dbase | (int)(p & 1023u);
    int s = (int)(p >> BINBITS);
    int slot = atomicAdd(&cursor[d], 1);
    srcs[slot] = s;
  }
}

// ---------------- Layer 1: tiled GEMM h = x @ W1, W in LDS, x broadcast-read from global ----------------
__global__ __launch_bounds__(256) void gemm1_k(const float* __restrict__ x, const float* __restrict__ W,
                                               const float* __restrict__ a_s, const float* __restrict__ a_d,
                                               unsigned* __restrict__ h1bf, float* __restrict__ asrc,
                                               float* __restrict__ adst, unsigned* __restrict__ gmaxg) {
  __shared__ float ldsW[128 * 64];     // W[k][c]
  __shared__ unsigned gm8[8];
  int t = threadIdx.x;
  int n0 = blockIdx.x * 64;
  if (t < 8) gm8[t] = 0;
  {
    const float4* W4 = (const float4*)W;
    float4* lw = (float4*)ldsW;
    #pragma unroll
    for (int r = 0; r < 8; r++) lw[r * 256 + t] = W4[r * 256 + t];
  }
  __syncthreads();
  int cg = t & 15, ng = t >> 4;        // 4 channels, 4 nodes per thread
  const float* xr0 = x + (size_t)min(n0 + ng * 4 + 0, NN - 1) * 128;
  const float* xr1 = x + (size_t)min(n0 + ng * 4 + 1, NN - 1) * 128;
  const float* xr2 = x + (size_t)min(n0 + ng * 4 + 2, NN - 1) * 128;
  const float* xr3 = x + (size_t)min(n0 + ng * 4 + 3, NN - 1) * 128;
  float acc[4][4] = {};
  #pragma unroll 4
  for (int k = 0; k < 128; k += 2) {
    float2 xv0 = *(const float2*)&xr0[k];
    float2 xv1 = *(const float2*)&xr1[k];
    float2 xv2 = *(const float2*)&xr2[k];
    float2 xv3 = *(const float2*)&xr3[k];
    float4 w0 = *(const float4*)&ldsW[k * 64 + cg * 4];
    float4 w1 = *(const float4*)&ldsW[(k + 1) * 64 + cg * 4];
    acc[0][0] += xv0.x * w0.x + xv0.y * w1.x;
    acc[0][1] += xv0.x * w0.y + xv0.y * w1.y;
    acc[0][2] += xv0.x * w0.z + xv0.y * w1.z;
    acc[0][3] += xv0.x * w0.w + xv0.y * w1.w;
    acc[1][0] += xv1.x * w0.x + xv1.y * w1.x;
    acc[1][1] += xv1.x * w0.y + xv1.y * w1.y;
    acc[1][2] += xv1.x * w0.z + xv1.y * w1.z;
    acc[1][3] += xv1.x * w0.w + xv1.y * w1.w;
    acc[2][0] += xv2.x * w0.x + xv2.y * w1.x;
    acc[2][1] += xv2.x * w0.y + xv2.y * w1.y;
    acc[2][2] += xv2.x * w0.z + xv2.y * w1.z;
    acc[2][3] += xv2.x * w0.w + xv2.y * w1.w;
    acc[3][0] += xv3.x * w0.x + xv3.y * w1.x;
    acc[3][1] += xv3.x * w0.y + xv3.y * w1.y;
    acc[3][2] += xv3.x * w0.z + xv3.y * w1.z;
    acc[3][3] += xv3.x * w0.w + xv3.y * w1.w;
  }
  int head = cg >> 1, sub = (cg & 1) * 4;
  float as0 = a_s[head * 8 + sub], as1 = a_s[head * 8 + sub + 1];
  float as2 = a_s[head * 8 + sub + 2], as3 = a_s[head * 8 + sub + 3];
  float ad0 = a_d[head * 8 + sub], ad1 = a_d[head * 8 + sub + 1];
  float ad2 = a_d[head * 8 + sub + 2], ad3 = a_d[head * 8 + sub + 3];
  #pragma unroll
  for (int i = 0; i < 4; i++) {
    float vs = acc[i][0] * as0 + acc[i][1] * as1 + acc[i][2] * as2 + acc[i][3] * as3;
    float vd = acc[i][0] * ad0 + acc[i][1] * ad1 + acc[i][2] * ad2 + acc[i][3] * ad3;
    vs += __shfl_xor(vs, 1, 64);
    vd += __shfl_xor(vd, 1, 64);
    vs *= LOG2E; vd *= LOG2E;     // pre-scale so agg can use exp2 directly
    int gn = n0 + ng * 4 + i;
    if (gn < NN) {
      unsigned p0 = bfr(acc[i][0]) | (bfr(acc[i][1]) << 16);
      unsigned p1 = bfr(acc[i][2]) | (bfr(acc[i][3]) << 16);
      ((uint2*)(h1bf + (size_t)gn * 32))[cg] = make_uint2(p0, p1);
      if ((cg & 1) == 0) {
        asrc[gn * 8 + head] = vs;
        adst[gn * 8 + head] = vd;
        atomicMax(&gm8[head], fkey(vs));
      }
    }
  }
  __syncthreads();
  if (t < 8) atomicMax(&gmaxg[t], gm8[t]);
}

// ---------------- Layer 1 aggregation: 4 edges/iter (16-lane groups), bf16 uint2 gather ----------------
__global__ __launch_bounds__(256) void agg1_k(const unsigned* __restrict__ h1bf, const float* __restrict__ asrc,
                                              const float* __restrict__ adst_, const int* __restrict__ indptr,
                                              const int* __restrict__ srcs, const float* __restrict__ b,
                                              const unsigned* __restrict__ gmax, float* __restrict__ z1) {
  int wave = threadIdx.x >> 6, lane = threadIdx.x & 63;
  int node = blockIdx.x * 4 + wave;
  int s0 = indptr[node], s1 = indptr[node + 1];
  int grp = lane >> 4, q = lane & 15;  // group handles edge j+grp; lane owns channels 4q..4q+3
  int head = q >> 1;
  float ad = adst_[node * 8 + head];
  float ub = gmax_decode(gmax[head]) + ad; ub = fmaxf(ub, 0.2f * ub);
  const uint2* hp = (const uint2*)h1bf;
  float d = 0.f, a0 = 0.f, a1 = 0.f, a2 = 0.f, a3 = 0.f;
  for (int base = s0; base < s1; base += 64) {
    int i = base + lane;
    int sv = (i < s1) ? srcs[i] : 0;
    int n = s1 - base; if (n > 64) n = 64;
    for (int j = 0; j < n; j += 4) {
      int jj = j + grp;
      int s = __shfl(sv, jj, 64);
      float e = asrc[s * 8 + head] + ad;
      e = fmaxf(e, 0.2f * e);
      float w = __builtin_amdgcn_exp2f(e - ub);
      if (jj >= n) w = 0.f;
      uint2 u = hp[(size_t)s * 16 + q];
      d += w;
      a0 += w * __uint_as_float(u.x << 16);
      a1 += w * __uint_as_float(u.x & 0xFFFF0000u);
      a2 += w * __uint_as_float(u.y << 16);
      a3 += w * __uint_as_float(u.y & 0xFFFF0000u);
    }
  }
  // reduce across the 4 edge-groups (bits 4,5); head-pair parity lanes hold duplicates (never summed)
  d  += __shfl_xor(d, 16, 64);  d  += __shfl_xor(d, 32, 64);
  a0 += __shfl_xor(a0, 16, 64); a0 += __shfl_xor(a0, 32, 64);
  a1 += __shfl_xor(a1, 16, 64); a1 += __shfl_xor(a1, 32, 64);
  a2 += __shfl_xor(a2, 16, 64); a2 += __shfl_xor(a2, 32, 64);
  a3 += __shfl_xor(a3, 16, 64); a3 += __shfl_xor(a3, 32, 64);
  if (grp == 0) {
    float inv = 1.f / (d + 1e-16f);
    float o0 = a0 * inv + b[4 * q];
    float o1 = a1 * inv + b[4 * q + 1];
    float o2 = a2 * inv + b[4 * q + 2];
    float o3 = a3 * inv + b[4 * q + 3];
    float4 ov;
    ov.x = o0 > 0.f ? o0 : 0.f;
    ov.y = o1 > 0.f ? o1 : 0.f;
    ov.z = o2 > 0.f ? o2 : 0.f;
    ov.w = o3 > 0.f ? o3 : 0.f;
    ((float4*)z1)[node * 16 + q] = ov;
  }
}

// ---------------- Layer 2: tiled GEMM h2 = z1 @ W2, W in LDS, z1 broadcast-read from global ----------------
__global__ __launch_bounds__(256) void gemm2_k(const float* __restrict__ z1, const float* __restrict__ W,
                                               const float* __restrict__ a_s, const float* __restrict__ a_d,
                                               uint2* __restrict__ h2bf, float* __restrict__ asrc,
                                               float* __restrict__ adst, unsigned* __restrict__ gmaxg) {
  __shared__ float ldsW[64 * 128];     // W[k][c]
  __shared__ unsigned gm8[8];
  int t = threadIdx.x;
  int n0 = blockIdx.x * 64;
  if (t < 8) gm8[t] = 0;
  {
    const float4* W4 = (const float4*)W;
    float4* lw = (float4*)ldsW;
    #pragma unroll
    for (int r = 0; r < 8; r++) lw[r * 256 + t] = W4[r * 256 + t];
  }
  __syncthreads();
  int cg = t & 15, ng = t >> 4;        // 8 channels, 4 nodes per thread
  int c0 = cg * 8;
  const float* zr0 = z1 + (size_t)min(n0 + ng * 4 + 0, NN - 1) * 64;
  const float* zr1 = z1 + (size_t)min(n0 + ng * 4 + 1, NN - 1) * 64;
  const float* zr2 = z1 + (size_t)min(n0 + ng * 4 + 2, NN - 1) * 64;
  const float* zr3 = z1 + (size_t)min(n0 + ng * 4 + 3, NN - 1) * 64;
  float acc[4][8] = {};
  #pragma unroll 2
  for (int k = 0; k < 64; k += 2) {
    float2 xv[4];
    xv[0] = *(const float2*)&zr0[k];
    xv[1] = *(const float2*)&zr1[k];
    xv[2] = *(const float2*)&zr2[k];
    xv[3] = *(const float2*)&zr3[k];
    float4 wa0 = *(const float4*)&ldsW[k * 128 + c0];
    float4 wa1 = *(const float4*)&ldsW[k * 128 + c0 + 4];
    float4 wb0 = *(const float4*)&ldsW[(k + 1) * 128 + c0];
    float4 wb1 = *(const float4*)&ldsW[(k + 1) * 128 + c0 + 4];
    #pragma unroll
    for (int i = 0; i < 4; i++) {
      acc[i][0] += xv[i].x * wa0.x + xv[i].y * wb0.x;
      acc[i][1] += xv[i].x * wa0.y + xv[i].y * wb0.y;
      acc[i][2] += xv[i].x * wa0.z + xv[i].y * wb0.z;
      acc[i][3] += xv[i].x * wa0.w + xv[i].y * wb0.w;
      acc[i][4] += xv[i].x * wa1.x + xv[i].y * wb1.x;
      acc[i][5] += xv[i].x * wa1.y + xv[i].y * wb1.y;
      acc[i][6] += xv[i].x * wa1.z + xv[i].y * wb1.z;
      acc[i][7] += xv[i].x * wa1.w + xv[i].y * wb1.w;
    }
  }
  int head = cg >> 1, sub = (cg & 1) * 8;
  float asv[8], adv[8];
  #pragma unroll
  for (int j = 0; j < 8; j++) {
    asv[j] = a_s[head * 16 + sub + j];
    adv[j] = a_d[head * 16 + sub + j];
  }
  #pragma unroll
  for (int i = 0; i < 4; i++) {
    float vs = 0.f, vd = 0.f;
    #pragma unroll
    for (int j = 0; j < 8; j++) { vs += acc[i][j] * asv[j]; vd += acc[i][j] * adv[j]; }
    vs += __shfl_xor(vs, 1, 64);
    vd += __shfl_xor(vd, 1, 64);
    vs *= LOG2E; vd *= LOG2E;
    int gn = n0 + ng * 4 + i;
    if (gn < NN) {
      unsigned p0 = bfr(acc[i][0]) | (bfr(acc[i][1]) << 16);
      unsigned p1 = bfr(acc[i][2]) | (bfr(acc[i][3]) << 16);
      unsigned p2 = bfr(acc[i][4]) | (bfr(acc[i][5]) << 16);
      unsigned p3 = bfr(acc[i][6]) | (bfr(acc[i][7]) << 16);
      ((uint4*)h2bf)[(size_t)gn * 16 + cg] = make_uint4(p0, p1, p2, p3);
      if ((cg & 1) == 0) {
        asrc[gn * 8 + head] = vs;
        adst[gn * 8 + head] = vd;
        atomicMax(&gm8[head], fkey(vs));
      }
    }
  }
  __syncthreads();
  if (t < 8) atomicMax(&gmaxg[t], gm8[t]);
}

// ---------------- Layer 2 aggregation: 4 edges/iter (16-lane groups), bf16 uint4 gather ----------------
__global__ __launch_bounds__(256) void agg2_k(const uint2* __restrict__ h2bf, const float* __restrict__ asrc,
                                              const float* __restrict__ adst_, const int* __restrict__ indptr,
                                              const int* __restrict__ srcs, const float* __restrict__ b,
                                              const unsigned* __restrict__ gmax, float* __restrict__ z2) {
  int wave = threadIdx.x >> 6, lane = threadIdx.x & 63;
  int node = blockIdx.x * 4 + wave;
  int s0 = indptr[node], s1 = indptr[node + 1];
  int grp = lane >> 4, q = lane & 15;  // group handles edge j+grp; lane owns channels 8q..8q+7
  int head = q >> 1;
  float ad = adst_[node * 8 + head];
  float ub = gmax_decode(gmax[head]) + ad; ub = fmaxf(ub, 0.2f * ub);
  const uint4* hp = (const uint4*)h2bf;
  float d = 0.f;
  float a0 = 0.f, a1 = 0.f, a2 = 0.f, a3 = 0.f, a4 = 0.f, a5 = 0.f, a6 = 0.f, a7 = 0.f;
  for (int base = s0; base < s1; base += 64) {
    int i = base + lane;
    int sv = (i < s1) ? srcs[i] : 0;
    int n = s1 - base; if (n > 64) n = 64;
    for (int j = 0; j < n; j += 4) {
      int jj = j + grp;
      int s = __shfl(sv, jj, 64);
      float e = asrc[s * 8 + head] + ad;
      e = fmaxf(e, 0.2f * e);
      float w = __builtin_amdgcn_exp2f(e - ub);
      if (jj >= n) w = 0.f;
      uint4 u = hp[(size_t)s * 16 + q];
      d += w;
      a0 += w * __uint_as_float(u.x << 16);
      a1 += w * __uint_as_float(u.x & 0xFFFF0000u);
      a2 += w * __uint_as_float(u.y << 16);
      a3 += w * __uint_as_float(u.y & 0xFFFF0000u);
      a4 += w * __uint_as_float(u.z << 16);
      a5 += w * __uint_as_float(u.z & 0xFFFF0000u);
      a6 += w * __uint_as_float(u.w << 16);
      a7 += w * __uint_as_float(u.w & 0xFFFF0000u);
    }
  }
  d  += __shfl_xor(d, 16, 64);  d  += __shfl_xor(d, 32, 64);
  a0 += __shfl_xor(a0, 16, 64); a0 += __shfl_xor(a0, 32, 64);
  a1 += __shfl_xor(a1, 16, 64); a1 += __shfl_xor(a1, 32, 64);
  a2 += __shfl_xor(a2, 16, 64); a2 += __shfl_xor(a2, 32, 64);
  a3 += __shfl_xor(a3, 16, 64); a3 += __shfl_xor(a3, 32, 64);
  a4 += __shfl_xor(a4, 16, 64); a4 += __shfl_xor(a4, 32, 64);
  a5 += __shfl_xor(a5, 16, 64); a5 += __shfl_xor(a5, 32, 64);
  a6 += __shfl_xor(a6, 16, 64); a6 += __shfl_xor(a6, 32, 64);
  a7 += __shfl_xor(a7, 16, 64); a7 += __shfl_xor(a7, 32, 64);
  if (grp == 0) {
    float inv = 1.f / (d + 1e-16f);
    float o0 = a0 * inv + b[8 * q];
    float o1 = a1 * inv + b[8 * q + 1];
    float o2 = a2 * inv + b[8 * q + 2];
    float o3 = a3 * inv + b[8 * q + 3];
    float o4 = a4 * inv + b[8 * q + 4];
    float o5 = a5 * inv + b[8 * q + 5];
    float o6 = a6 * inv + b[8 * q + 6];
    float o7 = a7 * inv + b[8 * q + 7];
    float4 v0, v1;
    v0.x = o0 > 0.f ? o0 : 0.f;
    v0.y = o1 > 0.f ? o1 : 0.f;
    v0.z = o2 > 0.f ? o2 : 0.f;
    v0.w = o3 > 0.f ? o3 : 0.f;
    v1.x = o4 > 0.f ? o4 : 0.f;
    v1.y = o5 > 0.f ? o5 : 0.f;
    v1.z = o6 > 0.f ? o6 : 0.f;
    v1.w = o7 > 0.f ? o7 : 0.f;
    ((float4*)z2)[node * 32 + 2 * q] = v0;
    ((float4*)z2)[node * 32 + 2 * q + 1] = v1;
  }
}

// ---------------- Mean pool: boundary-based, parallel ----------------
__global__ void gb_init_k(int* gstart) {
  int t = threadIdx.x;
  if (t <= NG) gstart[t] = NN;
}

__global__ void gb_min_k(const int* __restrict__ batch, int* __restrict__ gstart) {
  int i = blockIdx.x * 256 + threadIdx.x;
  if (i < NN) atomicMin(&gstart[batch[i]], i);
}

__global__ void gb_fix_k(int* __restrict__ gstart, float* __restrict__ gcnt) {
  if (threadIdx.x == 0) {
    gstart[NG] = NN;
    for (int g = NG - 1; g >= 0; g--)
      if (gstart[g] > gstart[g + 1]) gstart[g] = gstart[g + 1];  // empty graph
    for (int g = 0; g < NG; g++) gcnt[g] = (float)(gstart[g + 1] - gstart[g]);
  }
}

#define PSPL 8
__global__ __launch_bounds__(256) void pool2_k(const float* __restrict__ h, const int* __restrict__ gstart,
                                               float* __restrict__ sums) {
  __shared__ float4 red[256];
  int t = threadIdx.x;
  int g = blockIdx.x / PSPL, s = blockIdx.x % PSPL;
  int lo = gstart[g], hi = gstart[g + 1];
  int n = hi - lo;
  int per = (n + PSPL - 1) / PSPL;
  int i0 = lo + s * per;
  int i1 = min(i0 + per, hi);
  int c4 = t & 31, r = t >> 5;   // 32 float4-channels x 8 rows in flight
  const float4* h4 = (const float4*)h;
  float4 acc = make_float4(0.f, 0.f, 0.f, 0.f);
  for (int i = i0 + r; i < i1; i += 8) {
    float4 v = h4[(size_t)i * 32 + c4];
    acc.x += v.x; acc.y += v.y; acc.z += v.z; acc.w += v.w;
  }
  red[t] = acc;
  __syncthreads();
  for (int off = 4; off > 0; off >>= 1) {
    if (r < off) {
      float4 o = red[t + 32 * off];
      red[t].x += o.x; red[t].y += o.y; red[t].z += o.z; red[t].w += o.w;
    }
    __syncthreads();
  }
  if (r == 0) {
    float4 v = red[t];
    atomicAdd(&sums[g * 128 + c4 * 4 + 0], v.x);
    atomicAdd(&sums[g * 128 + c4 * 4 + 1], v.y);
    atomicAdd(&sums[g * 128 + c4 * 4 + 2], v.z);
    atomicAdd(&sums[g * 128 + c4 * 4 + 3], v.w);
  }
}

// mean-divide into fc1 input
__global__ void pooldiv_k(const float* __restrict__ sums, const float* __restrict__ cnts, float* __restrict__ g) {
  int i = blockIdx.x * 256 + threadIdx.x;
  if (i < NG * 128) {
    float c = cnts[i >> 7];
    c = c < 1.f ? 1.f : c;
    g[i] = sums[i] / c;
  }
}

// init MLP output buffers with bias (idempotent per launch; required since layers atomically accumulate)
__global__ void biasinit_k(float* __restrict__ t1, const float* __restrict__ bb1,
                           float* __restrict__ t2, const float* __restrict__ bb2,
                           float* __restrict__ t3, const float* __restrict__ bb3,
                           float* __restrict__ o, const float* __restrict__ bb4) {
  int i = blockIdx.x * 256 + threadIdx.x;
  if (i < NG * 256) t1[i] = bb1[i & 255];
  if (i < NG * 512) { t2[i] = bb2[i & 511]; t3[i] = bb3[i & 511]; }
  if (i < NG * 100) o[i] = bb4[i % 100];
}

// ---------------- MLP layer: split-k x split-col, atomic accumulate ----------------
// grid.x = col-tiles (16 cols), grid.y = k-chunks (64). out must be pre-initialized with bias.
template <int K, int OUT, bool RELU_IN>
__global__ __launch_bounds__(256) void mlps_k(const float* __restrict__ in, const float* __restrict__ W,
                                              float* __restrict__ out) {
  __shared__ float As[64][65];   // As[k][g], pad 65 -> conflict-free
  int t = threadIdx.x;
  int c0 = blockIdx.x * 16;
  int k0 = blockIdx.y * 64;
  #pragma unroll
  for (int r = 0; r < 16; r++) {
    int flat = r * 256 + t;
    int g = flat >> 6, k = flat & 63;
    float v = in[g * K + k0 + k];
    if (RELU_IN) v = fmaxf(v, 0.f);
    As[k][g] = v;
  }
  __syncthreads();
  int g = t & 63, cq = t >> 6;        // wave-uniform cq -> W reads broadcast
  int col = c0 + cq * 4;
  if (col < OUT) {
    float a0 = 0.f, a1 = 0.f, a2 = 0.f, a3 = 0.f;
    #pragma unroll 8
    for (int k = 0; k < 64; k++) {
      float av = As[k][g];
      float4 wv = *(const float4*)&W[(size_t)(k0 + k) * OUT + col];
      a0 += av * wv.x; a1 += av * wv.y; a2 += av * wv.z; a3 += av * wv.w;
    }
    atomicAdd(&out[g * OUT + col], a0);
    if (col + 1 < OUT) atomicAdd(&out[g * OUT + col + 1], a1);
    if (col + 2 < OUT) atomicAdd(&out[g * OUT + col + 2], a2);
    if (col + 3 < OUT) atomicAdd(&out[g * OUT + col + 3], a3);
  }
}

extern "C" void kernel_launch(void* const* d_in, const int* in_sizes, int n_in,
                              void* d_out, int out_size, void* d_ws, size_t ws_size,
                              hipStream_t stream) {
  const float* x      = (const float*)d_in[0];
  const int*   ei     = (const int*)d_in[1];
  const int*   batch  = (const int*)d_in[2];
  const float* W1     = (const float*)d_in[3];
  const float* a_src1 = (const float*)d_in[4];
  const float* a_dst1 = (const float*)d_in[5];
  const float* b1     = (const float*)d_in[6];
  const float* W2     = (const float*)d_in[7];
  const float* a_src2 = (const float*)d_in[8];
  const float* a_dst2 = (const float*)d_in[9];
  const float* b2     = (const float*)d_in[10];
  const float* fc1_w  = (const float*)d_in[11];
  const float* fc1_b  = (const float*)d_in[12];
  const float* fc2_w  = (const float*)d_in[13];
  const float* fc2_b  = (const float*)d_in[14];
  const float* fc3_w  = (const float*)d_in[15];
  const float* fc3_b  = (const float*)d_in[16];
  const float* fc4_w  = (const float*)d_in[17];
  const float* fc4_b  = (const float*)d_in[18];
  float* outp = (float*)d_out;

  // ---- workspace carve (phase-aliased) ----
  float* z2   = (float*)d_ws;                        // NN*128 f32 (region A)
  uint2* h2bf = (uint2*)(z2 + (size_t)NN * 128);     // NN*32 uint2
  float* asrc = (float*)(h2bf + (size_t)NN * 32);    // NN*8
  float* adst = asrc + (size_t)NN * 8;               // NN*8
  int* srcs   = (int*)(adst + (size_t)NN * 8);       // ET
  int* indptr = srcs + ET;                           // NN+1
  float* sums = (float*)(indptr + NN + 1);           // NG*128
  float* gcnt = sums + NG * 128;                     // NG
  float* mlpin = gcnt + NG;                          // NG*128 (fc1 input)
  float* mlpt1 = mlpin + NG * 128;                   // NG*256
  float* mlpt2 = mlpt1 + NG * 256;                   // NG*512
  float* mlpt3 = mlpt2 + NG * 512;                   // NG*512
  unsigned* gmax = (unsigned*)(mlpt3 + NG * 512);    // 8
  int* binbase = (int*)(gmax + 8);                   // NBINS+1
  int* bincur  = binbase + NBINS + 1;                // NBINS
  int* gstart  = bincur + NBINS;                     // NG+1
  // region-A aliases (phase 1: CSR build; phases 2-4: features)
  unsigned* binbuf = (unsigned*)z2;                  // ET   (phase 1 only)
  int* counts = (int*)z2 + ET;                       // NN   (phase 1 only)
  int* cursor = counts + NN;                         // NN   (phase 1 only)
  unsigned* h1bf = (unsigned*)z2;                    // NN*32 (phases 2-3)
  float* z1 = z2 + (size_t)NN * 32;                  // NN*64 (phases 3-4)

  const int NCH = (NN + 1023) / 1024;  // 98

  // CSR build (chunk sums staged in srcs[0..NCH), overwritten by binB)
  init_counts_k<<<(NN + 255) / 256, 256, 0, stream>>>(counts);
  count_k<<<(NE + 255) / 256, 256, 0, stream>>>(ei + NE, counts);
  scan1_k<<<NCH, 1024, 0, stream>>>(counts, srcs);
  scan2_k<<<1, 128, 0, stream>>>(srcs, NCH);
  scan3_k<<<NCH, 1024, 0, stream>>>(counts, srcs, indptr, cursor);
  bininit_k<<<1, 128, 0, stream>>>(indptr, binbase, bincur);
  binA_k<<<(ET + 256 * EPB - 1) / (256 * EPB), 256, 0, stream>>>(ei, bincur, binbuf);
  {
    int nq = (NBINS + 7) / 8;
    int grid = 8 * nq * SEGS;
    binB_k<<<grid, 256, 0, stream>>>(binbuf, binbase, cursor, srcs);
  }
  // graph boundaries (batch sorted)
  gb_init_k<<<1, 128, 0, stream>>>(gstart);
  gb_min_k<<<(NN + 255) / 256, 256, 0, stream>>>(batch, gstart);
  gb_fix_k<<<1, 64, 0, stream>>>(gstart, gcnt);

  const int NGEMM = (NN + 63) / 64;  // 1563

  // GAT layer 1
  hipMemsetAsync(gmax, 0, 8 * sizeof(unsigned), stream);
  gemm1_k<<<NGEMM, 256, 0, stream>>>(x, W1, a_src1, a_dst1, h1bf, asrc, adst, gmax);
  agg1_k<<<NN / 4, 256, 0, stream>>>(h1bf, asrc, adst, indptr, srcs, b1, gmax, z1);

  // GAT layer 2
  hipMemsetAsync(gmax, 0, 8 * sizeof(unsigned), stream);
  gemm2_k<<<NGEMM, 256, 0, stream>>>(z1, W2, a_src2, a_dst2, h2bf, asrc, adst, gmax);
  agg2_k<<<NN / 4, 256, 0, stream>>>(h2bf, asrc, adst, indptr, srcs, b2, gmax, z2);

  // mean pool (boundary-parallel) + MLP (split-k/col, bias-preinit, atomic accumulate)
  hipMemsetAsync(sums, 0, NG * 128 * sizeof(float), stream);
  pool2_k<<<NG * PSPL, 256, 0, stream>>>(z2, gstart, sums);
  pooldiv_k<<<(NG * 128 + 255) / 256, 256, 0, stream>>>(sums, gcnt, mlpin);
  biasinit_k<<<(NG * 512 + 255) / 256, 256, 0, stream>>>(mlpt1, fc1_b, mlpt2, fc2_b, mlpt3, fc3_b, outp, fc4_b);
  mlps_k<128, 256, false><<<dim3(16, 2), 256, 0, stream>>>(mlpin, fc1_w, mlpt1);
  mlps_k<256, 512, true><<<dim3(32, 4), 256, 0, stream>>>(mlpt1, fc2_w, mlpt2);
  mlps_k<512, 512, true><<<dim3(32, 8), 256, 0, stream>>>(mlpt2, fc3_w, mlpt3);
  mlps_k<512, 100, true><<<dim3(7, 8), 256, 0, stream>>>(mlpt3, fc4_w, outp);

  (void)in_sizes; (void)n_in; (void)out_size; (void)ws_size;
}

// Round 14
// 684.819 us; speedup vs baseline: 1.6117x; 1.6117x over previous
//
#include <hip/hip_runtime.h>
#include <hip/hip_bf16.h>

#define NN 100000
#define NE 3200000
#define ET (NE + NN)
#define NG 64
#define BINBITS 10
#define NBINS 98   // ceil(100000/1024)
#define EPB 16
#define LOG2E 1.44269504088896f

__device__ __forceinline__ unsigned bfr(float x) {  // fp32 -> bf16 bits, RNE
  unsigned u = __float_as_uint(x);
  return (u + 0x7FFFu + ((u >> 16) & 1u)) >> 16;
}

__device__ __forceinline__ unsigned fkey(float x) {  // orderable-uint encode
  unsigned b = __float_as_uint(x);
  return (b & 0x80000000u) ? ~b : (b | 0x80000000u);
}

__device__ __forceinline__ float gmax_decode(unsigned k) {
  return __uint_as_float((k & 0x80000000u) ? (k & 0x7FFFFFFFu) : ~k);
}

// ---------------- CSR build ----------------
__global__ void init_counts_k(int* counts) {
  int i = blockIdx.x * 256 + threadIdx.x;
  if (i < NN) counts[i] = 1;  // self loop
}

__global__ void count_k(const int* __restrict__ dst, int* __restrict__ counts) {
  int i = blockIdx.x * 256 + threadIdx.x;
  if (i < NE) atomicAdd(&counts[dst[i]], 1);
}

__global__ __launch_bounds__(1024) void scan1_k(const int* __restrict__ cnt, int* __restrict__ csum) {
  __shared__ int lds[1024];
  int i = blockIdx.x * 1024 + threadIdx.x;
  lds[threadIdx.x] = (i < NN) ? cnt[i] : 0;
  __syncthreads();
  for (int off = 512; off > 0; off >>= 1) {
    if (threadIdx.x < off) lds[threadIdx.x] += lds[threadIdx.x + off];
    __syncthreads();
  }
  if (threadIdx.x == 0) csum[blockIdx.x] = lds[0];
}

__global__ __launch_bounds__(128) void scan2_k(int* csum, int nch) {
  __shared__ int lds[128];
  int v = (threadIdx.x < nch) ? csum[threadIdx.x] : 0;
  lds[threadIdx.x] = v;
  __syncthreads();
  for (int off = 1; off < 128; off <<= 1) {
    int t = (threadIdx.x >= off) ? lds[threadIdx.x - off] : 0;
    __syncthreads();
    lds[threadIdx.x] += t;
    __syncthreads();
  }
  if (threadIdx.x < nch) csum[threadIdx.x] = lds[threadIdx.x] - v;  // exclusive
}

__global__ __launch_bounds__(1024) void scan3_k(const int* __restrict__ cnt, const int* __restrict__ csum,
                                                int* __restrict__ indptr, int* __restrict__ cursor) {
  __shared__ int lds[1024];
  int i = blockIdx.x * 1024 + threadIdx.x;
  int v = (i < NN) ? cnt[i] : 0;
  lds[threadIdx.x] = v;
  __syncthreads();
  for (int off = 1; off < 1024; off <<= 1) {
    int t = (threadIdx.x >= off) ? lds[threadIdx.x - off] : 0;
    __syncthreads();
    lds[threadIdx.x] += t;
    __syncthreads();
  }
  int excl = csum[blockIdx.x] + lds[threadIdx.x] - v;
  if (i < NN) { indptr[i] = excl; cursor[i] = excl; }
  else if (i == NN) indptr[NN] = ET;
}

__global__ void bininit_k(const int* __restrict__ indptr, int* __restrict__ binbase, int* __restrict__ bincur) {
  int b = threadIdx.x;
  if (b <= NBINS) {
    int node = b << BINBITS; if (node > NN) node = NN;
    int v = indptr[node];
    binbase[b] = v;
    if (b < NBINS) bincur[b] = v;
  }
}

// Pass A: bin edges by dst-range into staging buffer (packed (s<<10)|(d&1023))
__global__ __launch_bounds__(256) void binA_k(const int* __restrict__ ei, int* __restrict__ bincur,
                                              unsigned* __restrict__ binbuf) {
  __shared__ int lhist[NBINS], lbase[NBINS];
  int t = threadIdx.x;
  for (int i = t; i < NBINS; i += 256) lhist[i] = 0;
  __syncthreads();
  long base = (long)blockIdx.x * (256 * EPB);
  unsigned pk[EPB]; int bn[EPB];
  #pragma unroll
  for (int j = 0; j < EPB; j++) {
    long i = base + j * 256 + t;
    if (i < ET) {
      int s, d;
      if (i < NE) { s = ei[i]; d = ei[NE + i]; }
      else { s = (int)(i - NE); d = s; }
      int b = d >> BINBITS;
      bn[j] = b;
      pk[j] = ((unsigned)s << BINBITS) | (unsigned)(d & 1023);
      atomicAdd(&lhist[b], 1);
    } else bn[j] = -1;
  }
  __syncthreads();
  for (int i = t; i < NBINS; i += 256) {
    int c = lhist[i];
    lbase[i] = c ? atomicAdd(&bincur[i], c) : 0;
    lhist[i] = 0;
  }
  __syncthreads();
  #pragma unroll
  for (int j = 0; j < EPB; j++) {
    if (bn[j] >= 0) {
      int off = atomicAdd(&lhist[bn[j]], 1);
      binbuf[lbase[bn[j]] + off] = pk[j];
    }
  }
}

// Pass B: per-bin localized scatter to final CSR slots (L2-resident region per bin)
#define SEGS 8
__global__ __launch_bounds__(256) void binB_k(const unsigned* __restrict__ binbuf, const int* __restrict__ binbase,
                                              int* __restrict__ cursor, int* __restrict__ srcs) {
  int r = blockIdx.x & 7;
  int m = blockIdx.x >> 3;
  int q = m / SEGS, seg = m % SEGS;
  int bin = q * 8 + r;
  if (bin >= NBINS) return;
  int b0 = binbase[bin], b1 = binbase[bin + 1];
  int n = b1 - b0;
  int per = (n + SEGS - 1) / SEGS;
  int e0 = b0 + seg * per;
  int e1 = min(e0 + per, b1);
  int dbase = bin << BINBITS;
  for (int i = e0 + threadIdx.x; i < e1; i += 256) {
    unsigned p = binbuf[i];
    int d = dbase | (int)(p & 1023u);
    int s = (int)(p >> BINBITS);
    int slot = atomicAdd(&cursor[d], 1);
    srcs[slot] = s;
  }
}

// ---------------- Layer 1: tiled GEMM h = x @ W1, W in LDS, x broadcast-read from global ----------------
__global__ __launch_bounds__(256) void gemm1_k(const float* __restrict__ x, const float* __restrict__ W,
                                               const float* __restrict__ a_s, const float* __restrict__ a_d,
                                               unsigned* __restrict__ h1bf, float* __restrict__ asrc,
                                               float* __restrict__ adst, unsigned* __restrict__ gmaxg) {
  __shared__ float ldsW[128 * 64];     // W[k][c]
  __shared__ unsigned gm8[8];
  int t = threadIdx.x;
  int n0 = blockIdx.x * 64;
  if (t < 8) gm8[t] = 0;
  {
    const float4* W4 = (const float4*)W;
    float4* lw = (float4*)ldsW;
    #pragma unroll
    for (int r = 0; r < 8; r++) lw[r * 256 + t] = W4[r * 256 + t];
  }
  __syncthreads();
  int cg = t & 15, ng = t >> 4;        // 4 channels, 4 nodes per thread
  const float* xr0 = x + (size_t)min(n0 + ng * 4 + 0, NN - 1) * 128;
  const float* xr1 = x + (size_t)min(n0 + ng * 4 + 1, NN - 1) * 128;
  const float* xr2 = x + (size_t)min(n0 + ng * 4 + 2, NN - 1) * 128;
  const float* xr3 = x + (size_t)min(n0 + ng * 4 + 3, NN - 1) * 128;
  float acc[4][4] = {};
  #pragma unroll 4
  for (int k = 0; k < 128; k += 2) {
    float2 xv0 = *(const float2*)&xr0[k];
    float2 xv1 = *(const float2*)&xr1[k];
    float2 xv2 = *(const float2*)&xr2[k];
    float2 xv3 = *(const float2*)&xr3[k];
    float4 w0 = *(const float4*)&ldsW[k * 64 + cg * 4];
    float4 w1 = *(const float4*)&ldsW[(k + 1) * 64 + cg * 4];
    acc[0][0] += xv0.x * w0.x + xv0.y * w1.x;
    acc[0][1] += xv0.x * w0.y + xv0.y * w1.y;
    acc[0][2] += xv0.x * w0.z + xv0.y * w1.z;
    acc[0][3] += xv0.x * w0.w + xv0.y * w1.w;
    acc[1][0] += xv1.x * w0.x + xv1.y * w1.x;
    acc[1][1] += xv1.x * w0.y + xv1.y * w1.y;
    acc[1][2] += xv1.x * w0.z + xv1.y * w1.z;
    acc[1][3] += xv1.x * w0.w + xv1.y * w1.w;
    acc[2][0] += xv2.x * w0.x + xv2.y * w1.x;
    acc[2][1] += xv2.x * w0.y + xv2.y * w1.y;
    acc[2][2] += xv2.x * w0.z + xv2.y * w1.z;
    acc[2][3] += xv2.x * w0.w + xv2.y * w1.w;
    acc[3][0] += xv3.x * w0.x + xv3.y * w1.x;
    acc[3][1] += xv3.x * w0.y + xv3.y * w1.y;
    acc[3][2] += xv3.x * w0.z + xv3.y * w1.z;
    acc[3][3] += xv3.x * w0.w + xv3.y * w1.w;
  }
  int head = cg >> 1, sub = (cg & 1) * 4;
  float as0 = a_s[head * 8 + sub], as1 = a_s[head * 8 + sub + 1];
  float as2 = a_s[head * 8 + sub + 2], as3 = a_s[head * 8 + sub + 3];
  float ad0 = a_d[head * 8 + sub], ad1 = a_d[head * 8 + sub + 1];
  float ad2 = a_d[head * 8 + sub + 2], ad3 = a_d[head * 8 + sub + 3];
  #pragma unroll
  for (int i = 0; i < 4; i++) {
    float vs = acc[i][0] * as0 + acc[i][1] * as1 + acc[i][2] * as2 + acc[i][3] * as3;
    float vd = acc[i][0] * ad0 + acc[i][1] * ad1 + acc[i][2] * ad2 + acc[i][3] * ad3;
    vs += __shfl_xor(vs, 1, 64);
    vd += __shfl_xor(vd, 1, 64);
    vs *= LOG2E; vd *= LOG2E;     // pre-scale so agg can use exp2 directly
    int gn = n0 + ng * 4 + i;
    if (gn < NN) {
      unsigned p0 = bfr(acc[i][0]) | (bfr(acc[i][1]) << 16);
      unsigned p1 = bfr(acc[i][2]) | (bfr(acc[i][3]) << 16);
      ((uint2*)(h1bf + (size_t)gn * 32))[cg] = make_uint2(p0, p1);
      if ((cg & 1) == 0) {
        asrc[gn * 8 + head] = vs;
        adst[gn * 8 + head] = vd;
        atomicMax(&gm8[head], fkey(vs));
      }
    }
  }
  __syncthreads();
  if (t < 8) atomicMax(&gmaxg[t], gm8[t]);
}

// ---------------- Layer 1 aggregation: 4 edges/iter (16-lane groups), bf16 uint2 gather ----------------
__global__ __launch_bounds__(256) void agg1_k(const unsigned* __restrict__ h1bf, const float* __restrict__ asrc,
                                              const float* __restrict__ adst_, const int* __restrict__ indptr,
                                              const int* __restrict__ srcs, const float* __restrict__ b,
                                              const unsigned* __restrict__ gmax, float* __restrict__ z1) {
  int wave = threadIdx.x >> 6, lane = threadIdx.x & 63;
  int node = blockIdx.x * 4 + wave;
  int s0 = indptr[node], s1 = indptr[node + 1];
  int grp = lane >> 4, q = lane & 15;  // group handles edge j+grp; lane owns channels 4q..4q+3
  int head = q >> 1;
  float ad = adst_[node * 8 + head];
  float ub = gmax_decode(gmax[head]) + ad; ub = fmaxf(ub, 0.2f * ub);
  const uint2* hp = (const uint2*)h1bf;
  float d = 0.f, a0 = 0.f, a1 = 0.f, a2 = 0.f, a3 = 0.f;
  for (int base = s0; base < s1; base += 64) {
    int i = base + lane;
    int sv = (i < s1) ? srcs[i] : 0;
    int n = s1 - base; if (n > 64) n = 64;
    for (int j = 0; j < n; j += 4) {
      int jj = j + grp;
      int s = __shfl(sv, jj, 64);
      float e = asrc[s * 8 + head] + ad;
      e = fmaxf(e, 0.2f * e);
      float w = __builtin_amdgcn_exp2f(e - ub);
      if (jj >= n) w = 0.f;
      uint2 u = hp[(size_t)s * 16 + q];
      d += w;
      a0 += w * __uint_as_float(u.x << 16);
      a1 += w * __uint_as_float(u.x & 0xFFFF0000u);
      a2 += w * __uint_as_float(u.y << 16);
      a3 += w * __uint_as_float(u.y & 0xFFFF0000u);
    }
  }
  // reduce across the 4 edge-groups (bits 4,5); head-pair parity lanes hold duplicates (never summed)
  d  += __shfl_xor(d, 16, 64);  d  += __shfl_xor(d, 32, 64);
  a0 += __shfl_xor(a0, 16, 64); a0 += __shfl_xor(a0, 32, 64);
  a1 += __shfl_xor(a1, 16, 64); a1 += __shfl_xor(a1, 32, 64);
  a2 += __shfl_xor(a2, 16, 64); a2 += __shfl_xor(a2, 32, 64);
  a3 += __shfl_xor(a3, 16, 64); a3 += __shfl_xor(a3, 32, 64);
  if (grp == 0) {
    float inv = 1.f / (d + 1e-16f);
    float o0 = a0 * inv + b[4 * q];
    float o1 = a1 * inv + b[4 * q + 1];
    float o2 = a2 * inv + b[4 * q + 2];
    float o3 = a3 * inv + b[4 * q + 3];
    float4 ov;
    ov.x = o0 > 0.f ? o0 : 0.f;
    ov.y = o1 > 0.f ? o1 : 0.f;
    ov.z = o2 > 0.f ? o2 : 0.f;
    ov.w = o3 > 0.f ? o3 : 0.f;
    ((float4*)z1)[node * 16 + q] = ov;
  }
}

// ---------------- Layer 2: tiled GEMM h2 = z1 @ W2, W in LDS, z1 broadcast-read from global ----------------
__global__ __launch_bounds__(256) void gemm2_k(const float* __restrict__ z1, const float* __restrict__ W,
                                               const float* __restrict__ a_s, const float* __restrict__ a_d,
                                               uint2* __restrict__ h2bf, float* __restrict__ asrc,
                                               float* __restrict__ adst, unsigned* __restrict__ gmaxg) {
  __shared__ float ldsW[64 * 128];     // W[k][c]
  __shared__ unsigned gm8[8];
  int t = threadIdx.x;
  int n0 = blockIdx.x * 64;
  if (t < 8) gm8[t] = 0;
  {
    const float4* W4 = (const float4*)W;
    float4* lw = (float4*)ldsW;
    #pragma unroll
    for (int r = 0; r < 8; r++) lw[r * 256 + t] = W4[r * 256 + t];
  }
  __syncthreads();
  int cg = t & 15, ng = t >> 4;        // 8 channels, 4 nodes per thread
  int c0 = cg * 8;
  const float* zr0 = z1 + (size_t)min(n0 + ng * 4 + 0, NN - 1) * 64;
  const float* zr1 = z1 + (size_t)min(n0 + ng * 4 + 1, NN - 1) * 64;
  const float* zr2 = z1 + (size_t)min(n0 + ng * 4 + 2, NN - 1) * 64;
  const float* zr3 = z1 + (size_t)min(n0 + ng * 4 + 3, NN - 1) * 64;
  float acc[4][8] = {};
  #pragma unroll 2
  for (int k = 0; k < 64; k += 2) {
    float2 xv[4];
    xv[0] = *(const float2*)&zr0[k];
    xv[1] = *(const float2*)&zr1[k];
    xv[2] = *(const float2*)&zr2[k];
    xv[3] = *(const float2*)&zr3[k];
    float4 wa0 = *(const float4*)&ldsW[k * 128 + c0];
    float4 wa1 = *(const float4*)&ldsW[k * 128 + c0 + 4];
    float4 wb0 = *(const float4*)&ldsW[(k + 1) * 128 + c0];
    float4 wb1 = *(const float4*)&ldsW[(k + 1) * 128 + c0 + 4];
    #pragma unroll
    for (int i = 0; i < 4; i++) {
      acc[i][0] += xv[i].x * wa0.x + xv[i].y * wb0.x;
      acc[i][1] += xv[i].x * wa0.y + xv[i].y * wb0.y;
      acc[i][2] += xv[i].x * wa0.z + xv[i].y * wb0.z;
      acc[i][3] += xv[i].x * wa0.w + xv[i].y * wb0.w;
      acc[i][4] += xv[i].x * wa1.x + xv[i].y * wb1.x;
      acc[i][5] += xv[i].x * wa1.y + xv[i].y * wb1.y;
      acc[i][6] += xv[i].x * wa1.z + xv[i].y * wb1.z;
      acc[i][7] += xv[i].x * wa1.w + xv[i].y * wb1.w;
    }
  }
  int head = cg >> 1, sub = (cg & 1) * 8;
  float asv[8], adv[8];
  #pragma unroll
  for (int j = 0; j < 8; j++) {
    asv[j] = a_s[head * 16 + sub + j];
    adv[j] = a_d[head * 16 + sub + j];
  }
  #pragma unroll
  for (int i = 0; i < 4; i++) {
    float vs = 0.f, vd = 0.f;
    #pragma unroll
    for (int j = 0; j < 8; j++) { vs += acc[i][j] * asv[j]; vd += acc[i][j] * adv[j]; }
    vs += __shfl_xor(vs, 1, 64);
    vd += __shfl_xor(vd, 1, 64);
    vs *= LOG2E; vd *= LOG2E;
    int gn = n0 + ng * 4 + i;
    if (gn < NN) {
      unsigned p0 = bfr(acc[i][0]) | (bfr(acc[i][1]) << 16);
      unsigned p1 = bfr(acc[i][2]) | (bfr(acc[i][3]) << 16);
      unsigned p2 = bfr(acc[i][4]) | (bfr(acc[i][5]) << 16);
      unsigned p3 = bfr(acc[i][6]) | (bfr(acc[i][7]) << 16);
      ((uint4*)h2bf)[(size_t)gn * 16 + cg] = make_uint4(p0, p1, p2, p3);
      if ((cg & 1) == 0) {
        asrc[gn * 8 + head] = vs;
        adst[gn * 8 + head] = vd;
        atomicMax(&gm8[head], fkey(vs));
      }
    }
  }
  __syncthreads();
  if (t < 8) atomicMax(&gmaxg[t], gm8[t]);
}

// ---------------- Layer 2 aggregation: 4 edges/iter (16-lane groups), bf16 uint4 gather ----------------
__global__ __launch_bounds__(256) void agg2_k(const uint2* __restrict__ h2bf, const float* __restrict__ asrc,
                                              const float* __restrict__ adst_, const int* __restrict__ indptr,
                                              const int* __restrict__ srcs, const float* __restrict__ b,
                                              const unsigned* __restrict__ gmax, float* __restrict__ z2) {
  int wave = threadIdx.x >> 6, lane = threadIdx.x & 63;
  int node = blockIdx.x * 4 + wave;
  int s0 = indptr[node], s1 = indptr[node + 1];
  int grp = lane >> 4, q = lane & 15;  // group handles edge j+grp; lane owns channels 8q..8q+7
  int head = q >> 1;
  float ad = adst_[node * 8 + head];
  float ub = gmax_decode(gmax[head]) + ad; ub = fmaxf(ub, 0.2f * ub);
  const uint4* hp = (const uint4*)h2bf;
  float d = 0.f;
  float a0 = 0.f, a1 = 0.f, a2 = 0.f, a3 = 0.f, a4 = 0.f, a5 = 0.f, a6 = 0.f, a7 = 0.f;
  for (int base = s0; base < s1; base += 64) {
    int i = base + lane;
    int sv = (i < s1) ? srcs[i] : 0;
    int n = s1 - base; if (n > 64) n = 64;
    for (int j = 0; j < n; j += 4) {
      int jj = j + grp;
      int s = __shfl(sv, jj, 64);
      float e = asrc[s * 8 + head] + ad;
      e = fmaxf(e, 0.2f * e);
      float w = __builtin_amdgcn_exp2f(e - ub);
      if (jj >= n) w = 0.f;
      uint4 u = hp[(size_t)s * 16 + q];
      d += w;
      a0 += w * __uint_as_float(u.x << 16);
      a1 += w * __uint_as_float(u.x & 0xFFFF0000u);
      a2 += w * __uint_as_float(u.y << 16);
      a3 += w * __uint_as_float(u.y & 0xFFFF0000u);
      a4 += w * __uint_as_float(u.z << 16);
      a5 += w * __uint_as_float(u.z & 0xFFFF0000u);
      a6 += w * __uint_as_float(u.w << 16);
      a7 += w * __uint_as_float(u.w & 0xFFFF0000u);
    }
  }
  d  += __shfl_xor(d, 16, 64);  d  += __shfl_xor(d, 32, 64);
  a0 += __shfl_xor(a0, 16, 64); a0 += __shfl_xor(a0, 32, 64);
  a1 += __shfl_xor(a1, 16, 64); a1 += __shfl_xor(a1, 32, 64);
  a2 += __shfl_xor(a2, 16, 64); a2 += __shfl_xor(a2, 32, 64);
  a3 += __shfl_xor(a3, 16, 64); a3 += __shfl_xor(a3, 32, 64);
  a4 += __shfl_xor(a4, 16, 64); a4 += __shfl_xor(a4, 32, 64);
  a5 += __shfl_xor(a5, 16, 64); a5 += __shfl_xor(a5, 32, 64);
  a6 += __shfl_xor(a6, 16, 64); a6 += __shfl_xor(a6, 32, 64);
  a7 += __shfl_xor(a7, 16, 64); a7 += __shfl_xor(a7, 32, 64);
  if (grp == 0) {
    float inv = 1.f / (d + 1e-16f);
    float o0 = a0 * inv + b[8 * q];
    float o1 = a1 * inv + b[8 * q + 1];
    float o2 = a2 * inv + b[8 * q + 2];
    float o3 = a3 * inv + b[8 * q + 3];
    float o4 = a4 * inv + b[8 * q + 4];
    float o5 = a5 * inv + b[8 * q + 5];
    float o6 = a6 * inv + b[8 * q + 6];
    float o7 = a7 * inv + b[8 * q + 7];
    float4 v0, v1;
    v0.x = o0 > 0.f ? o0 : 0.f;
    v0.y = o1 > 0.f ? o1 : 0.f;
    v0.z = o2 > 0.f ? o2 : 0.f;
    v0.w = o3 > 0.f ? o3 : 0.f;
    v1.x = o4 > 0.f ? o4 : 0.f;
    v1.y = o5 > 0.f ? o5 : 0.f;
    v1.z = o6 > 0.f ? o6 : 0.f;
    v1.w = o7 > 0.f ? o7 : 0.f;
    ((float4*)z2)[node * 32 + 2 * q] = v0;
    ((float4*)z2)[node * 32 + 2 * q + 1] = v1;
  }
}

// ---------------- Mean pool: boundary-based, parallel ----------------
__global__ void gb_init_k(int* gstart) {
  int t = threadIdx.x;
  if (t <= NG) gstart[t] = NN;
}

// batch is sorted: graph g starts where the value changes. Exactly one writer per graph, no atomics.
__global__ void gb_bound_k(const int* __restrict__ batch, int* __restrict__ gstart) {
  int i = blockIdx.x * 256 + threadIdx.x;
  if (i >= NN) return;
  int g = batch[i];
  if (i == 0 || batch[i - 1] != g) gstart[g] = i;
}

__global__ void gb_fix_k(int* __restrict__ gstart, float* __restrict__ gcnt) {
  if (threadIdx.x == 0) {
    gstart[NG] = NN;
    for (int g = NG - 1; g >= 0; g--)
      if (gstart[g] > gstart[g + 1]) gstart[g] = gstart[g + 1];  // empty graph
    for (int g = 0; g < NG; g++) gcnt[g] = (float)(gstart[g + 1] - gstart[g]);
  }
}

#define PSPL 8
__global__ __launch_bounds__(256) void pool2_k(const float* __restrict__ h, const int* __restrict__ gstart,
                                               float* __restrict__ sums) {
  __shared__ float4 red[256];
  int t = threadIdx.x;
  int g = blockIdx.x / PSPL, s = blockIdx.x % PSPL;
  int lo = gstart[g], hi = gstart[g + 1];
  int n = hi - lo;
  int per = (n + PSPL - 1) / PSPL;
  int i0 = lo + s * per;
  int i1 = min(i0 + per, hi);
  int c4 = t & 31, r = t >> 5;   // 32 float4-channels x 8 rows in flight
  const float4* h4 = (const float4*)h;
  float4 acc = make_float4(0.f, 0.f, 0.f, 0.f);
  for (int i = i0 + r; i < i1; i += 8) {
    float4 v = h4[(size_t)i * 32 + c4];
    acc.x += v.x; acc.y += v.y; acc.z += v.z; acc.w += v.w;
  }
  red[t] = acc;
  __syncthreads();
  for (int off = 4; off > 0; off >>= 1) {
    if (r < off) {
      float4 o = red[t + 32 * off];
      red[t].x += o.x; red[t].y += o.y; red[t].z += o.z; red[t].w += o.w;
    }
    __syncthreads();
  }
  if (r == 0) {
    float4 v = red[t];
    atomicAdd(&sums[g * 128 + c4 * 4 + 0], v.x);
    atomicAdd(&sums[g * 128 + c4 * 4 + 1], v.y);
    atomicAdd(&sums[g * 128 + c4 * 4 + 2], v.z);
    atomicAdd(&sums[g * 128 + c4 * 4 + 3], v.w);
  }
}

// mean-divide into fc1 input
__global__ void pooldiv_k(const float* __restrict__ sums, const float* __restrict__ cnts, float* __restrict__ g) {
  int i = blockIdx.x * 256 + threadIdx.x;
  if (i < NG * 128) {
    float c = cnts[i >> 7];
    c = c < 1.f ? 1.f : c;
    g[i] = sums[i] / c;
  }
}

// init MLP output buffers with bias (idempotent per launch; required since layers atomically accumulate)
__global__ void biasinit_k(float* __restrict__ t1, const float* __restrict__ bb1,
                           float* __restrict__ t2, const float* __restrict__ bb2,
                           float* __restrict__ t3, const float* __restrict__ bb3,
                           float* __restrict__ o, const float* __restrict__ bb4) {
  int i = blockIdx.x * 256 + threadIdx.x;
  if (i < NG * 256) t1[i] = bb1[i & 255];
  if (i < NG * 512) { t2[i] = bb2[i & 511]; t3[i] = bb3[i & 511]; }
  if (i < NG * 100) o[i] = bb4[i % 100];
}

// ---------------- MLP layer: split-k x split-col, atomic accumulate ----------------
// grid.x = col-tiles (16 cols), grid.y = k-chunks (64). out must be pre-initialized with bias.
template <int K, int OUT, bool RELU_IN>
__global__ __launch_bounds__(256) void mlps_k(const float* __restrict__ in, const float* __restrict__ W,
                                              float* __restrict__ out) {
  __shared__ float As[64][65];   // As[k][g], pad 65 -> conflict-free
  int t = threadIdx.x;
  int c0 = blockIdx.x * 16;
  int k0 = blockIdx.y * 64;
  #pragma unroll
  for (int r = 0; r < 16; r++) {
    int flat = r * 256 + t;
    int g = flat >> 6, k = flat & 63;
    float v = in[g * K + k0 + k];
    if (RELU_IN) v = fmaxf(v, 0.f);
    As[k][g] = v;
  }
  __syncthreads();
  int g = t & 63, cq = t >> 6;        // wave-uniform cq -> W reads broadcast
  int col = c0 + cq * 4;
  if (col < OUT) {
    float a0 = 0.f, a1 = 0.f, a2 = 0.f, a3 = 0.f;
    #pragma unroll 8
    for (int k = 0; k < 64; k++) {
      float av = As[k][g];
      float4 wv = *(const float4*)&W[(size_t)(k0 + k) * OUT + col];
      a0 += av * wv.x; a1 += av * wv.y; a2 += av * wv.z; a3 += av * wv.w;
    }
    atomicAdd(&out[g * OUT + col], a0);
    if (col + 1 < OUT) atomicAdd(&out[g * OUT + col + 1], a1);
    if (col + 2 < OUT) atomicAdd(&out[g * OUT + col + 2], a2);
    if (col + 3 < OUT) atomicAdd(&out[g * OUT + col + 3], a3);
  }
}

extern "C" void kernel_launch(void* const* d_in, const int* in_sizes, int n_in,
                              void* d_out, int out_size, void* d_ws, size_t ws_size,
                              hipStream_t stream) {
  const float* x      = (const float*)d_in[0];
  const int*   ei     = (const int*)d_in[1];
  const int*   batch  = (const int*)d_in[2];
  const float* W1     = (const float*)d_in[3];
  const float* a_src1 = (const float*)d_in[4];
  const float* a_dst1 = (const float*)d_in[5];
  const float* b1     = (const float*)d_in[6];
  const float* W2     = (const float*)d_in[7];
  const float* a_src2 = (const float*)d_in[8];
  const float* a_dst2 = (const float*)d_in[9];
  const float* b2     = (const float*)d_in[10];
  const float* fc1_w  = (const float*)d_in[11];
  const float* fc1_b  = (const float*)d_in[12];
  const float* fc2_w  = (const float*)d_in[13];
  const float* fc2_b  = (const float*)d_in[14];
  const float* fc3_w  = (const float*)d_in[15];
  const float* fc3_b  = (const float*)d_in[16];
  const float* fc4_w  = (const float*)d_in[17];
  const float* fc4_b  = (const float*)d_in[18];
  float* outp = (float*)d_out;

  // ---- workspace carve (phase-aliased) ----
  float* z2   = (float*)d_ws;                        // NN*128 f32 (region A)
  uint2* h2bf = (uint2*)(z2 + (size_t)NN * 128);     // NN*32 uint2
  float* asrc = (float*)(h2bf + (size_t)NN * 32);    // NN*8
  float* adst = asrc + (size_t)NN * 8;               // NN*8
  int* srcs   = (int*)(adst + (size_t)NN * 8);       // ET
  int* indptr = srcs + ET;                           // NN+1
  float* sums = (float*)(indptr + NN + 1);           // NG*128
  float* gcnt = sums + NG * 128;                     // NG
  float* mlpin = gcnt + NG;                          // NG*128 (fc1 input)
  float* mlpt1 = mlpin + NG * 128;                   // NG*256
  float* mlpt2 = mlpt1 + NG * 256;                   // NG*512
  float* mlpt3 = mlpt2 + NG * 512;                   // NG*512
  unsigned* gmax = (unsigned*)(mlpt3 + NG * 512);    // 8
  int* binbase = (int*)(gmax + 8);                   // NBINS+1
  int* bincur  = binbase + NBINS + 1;                // NBINS
  int* gstart  = bincur + NBINS;                     // NG+1
  // region-A aliases (phase 1: CSR build; phases 2-4: features)
  unsigned* binbuf = (unsigned*)z2;                  // ET   (phase 1 only)
  int* counts = (int*)z2 + ET;                       // NN   (phase 1 only)
  int* cursor = counts + NN;                         // NN   (phase 1 only)
  unsigned* h1bf = (unsigned*)z2;                    // NN*32 (phases 2-3)
  float* z1 = z2 + (size_t)NN * 32;                  // NN*64 (phases 3-4)

  const int NCH = (NN + 1023) / 1024;  // 98

  // CSR build (chunk sums staged in srcs[0..NCH), overwritten by binB)
  init_counts_k<<<(NN + 255) / 256, 256, 0, stream>>>(counts);
  count_k<<<(NE + 255) / 256, 256, 0, stream>>>(ei + NE, counts);
  scan1_k<<<NCH, 1024, 0, stream>>>(counts, srcs);
  scan2_k<<<1, 128, 0, stream>>>(srcs, NCH);
  scan3_k<<<NCH, 1024, 0, stream>>>(counts, srcs, indptr, cursor);
  bininit_k<<<1, 128, 0, stream>>>(indptr, binbase, bincur);
  binA_k<<<(ET + 256 * EPB - 1) / (256 * EPB), 256, 0, stream>>>(ei, bincur, binbuf);
  {
    int nq = (NBINS + 7) / 8;
    int grid = 8 * nq * SEGS;
    binB_k<<<grid, 256, 0, stream>>>(binbuf, binbase, cursor, srcs);
  }
  // graph boundaries (batch sorted; boundary-detect, no atomics)
  gb_init_k<<<1, 128, 0, stream>>>(gstart);
  gb_bound_k<<<(NN + 255) / 256, 256, 0, stream>>>(batch, gstart);
  gb_fix_k<<<1, 64, 0, stream>>>(gstart, gcnt);

  const int NGEMM = (NN + 63) / 64;  // 1563

  // GAT layer 1
  hipMemsetAsync(gmax, 0, 8 * sizeof(unsigned), stream);
  gemm1_k<<<NGEMM, 256, 0, stream>>>(x, W1, a_src1, a_dst1, h1bf, asrc, adst, gmax);
  agg1_k<<<NN / 4, 256, 0, stream>>>(h1bf, asrc, adst, indptr, srcs, b1, gmax, z1);

  // GAT layer 2
  hipMemsetAsync(gmax, 0, 8 * sizeof(unsigned), stream);
  gemm2_k<<<NGEMM, 256, 0, stream>>>(z1, W2, a_src2, a_dst2, h2bf, asrc, adst, gmax);
  agg2_k<<<NN / 4, 256, 0, stream>>>(h2bf, asrc, adst, indptr, srcs, b2, gmax, z2);

  // mean pool (boundary-parallel) + MLP (split-k/col, bias-preinit, atomic accumulate)
  hipMemsetAsync(sums, 0, NG * 128 * sizeof(float), stream);
  pool2_k<<<NG * PSPL, 256, 0, stream>>>(z2, gstart, sums);
  pooldiv_k<<<(NG * 128 + 255) / 256, 256, 0, stream>>>(sums, gcnt, mlpin);
  biasinit_k<<<(NG * 512 + 255) / 256, 256, 0, stream>>>(mlpt1, fc1_b, mlpt2, fc2_b, mlpt3, fc3_b, outp, fc4_b);
  mlps_k<128, 256, false><<<dim3(16, 2), 256, 0, stream>>>(mlpin, fc1_w, mlpt1);
  mlps_k<256, 512, true><<<dim3(32, 4), 256, 0, stream>>>(mlpt1, fc2_w, mlpt2);
  mlps_k<512, 512, true><<<dim3(32, 8), 256, 0, stream>>>(mlpt2, fc3_w, mlpt3);
  mlps_k<512, 100, true><<<dim3(7, 8), 256, 0, stream>>>(mlpt3, fc4_w, outp);

  (void)in_sizes; (void)n_in; (void)out_size; (void)ws_size;
}